// Round 6
// baseline (146.482 us; speedup 1.0000x reference)
//
#include <hip/hip_runtime.h>
#include <hip/hip_bf16.h>

#define BDIM 8192
#define DDIM 256

typedef __attribute__((ext_vector_type(8))) short  s16x8;   // 8 x bf16 (4 VGPRs)
typedef __attribute__((ext_vector_type(4))) float  f32x4;   // MFMA accumulator

__device__ inline ushort f2bf(float x) {
    __hip_bfloat16 h = __float2bfloat16(x);
    ushort u;
    __builtin_memcpy(&u, &h, 2);
    return u;
}

// ---------------------------------------------------------------------------
// Kernel A: per-row stats + fragment-swizzled bf16 a_hat (layout-1).
//   u16 index(row,d) = (row>>4)*4096 + (d>>5)*512 + ((d>>3)&3)*128
//                      + (row&15)*8 + (d&7)
// (verified R2-R5, absmax 0.0)
// ---------------------------------------------------------------------------
__global__ __launch_bounds__(256) void row_stats(
    const float* __restrict__ A, const float* __restrict__ P,
    const float* __restrict__ N, ushort* __restrict__ Asw,
    float* __restrict__ partial_trip)
{
    __shared__ float tsh[4];
    const int wave = threadIdx.x >> 6;
    const int lane = threadIdx.x & 63;
    const int row  = blockIdx.x * 4 + wave;

    const float4 a = *(reinterpret_cast<const float4*>(A + (size_t)row * DDIM) + lane);
    const float4 p = *(reinterpret_cast<const float4*>(P + (size_t)row * DDIM) + lane);
    const float4 n = *(reinterpret_cast<const float4*>(N + (size_t)row * DDIM) + lane);

    float sa = a.x*a.x + a.y*a.y + a.z*a.z + a.w*a.w;

    float d0 = a.x - p.x + 1e-6f, d1 = a.y - p.y + 1e-6f;
    float d2 = a.z - p.z + 1e-6f, d3 = a.w - p.w + 1e-6f;
    float sp = d0*d0 + d1*d1 + d2*d2 + d3*d3;

    d0 = a.x - n.x + 1e-6f; d1 = a.y - n.y + 1e-6f;
    d2 = a.z - n.z + 1e-6f; d3 = a.w - n.w + 1e-6f;
    float sn = d0*d0 + d1*d1 + d2*d2 + d3*d3;

    #pragma unroll
    for (int off = 32; off > 0; off >>= 1) {
        sa += __shfl_xor(sa, off);
        sp += __shfl_xor(sp, off);
        sn += __shfl_xor(sn, off);
    }

    const float inv = 1.0f / fmaxf(sqrtf(sa), 1e-8f);

    ushort4 hv;
    hv.x = f2bf(a.x * inv);
    hv.y = f2bf(a.y * inv);
    hv.z = f2bf(a.z * inv);
    hv.w = f2bf(a.w * inv);
    const size_t chunk = ((size_t)(row >> 4) * 8 + (lane >> 3)) * 64
                       + (size_t)(((lane >> 1) & 3) * 16 + (row & 15));
    *reinterpret_cast<ushort4*>(Asw + chunk * 8 + (lane & 1) * 4) = hv;

    if (lane == 0)
        tsh[wave] = fmaxf(sqrtf(sp) - sqrtf(sn) + 0.2f, 0.0f);
    __syncthreads();
    if (threadIdx.x == 0)
        partial_trip[blockIdx.x] = tsh[0] + tsh[1] + tsh[2] + tsh[3];
}

// ---------------------------------------------------------------------------
// Kernel T: build layout-2 (A_hat^T fragment chunks) from layout-1.
//   Layout-2 chunk-block (d0>>4, j0>>5): u16 base = ((d0>>4)*256 + (j0>>5))*512;
//   lane l (fr=l&15, kg=l>>4) holds 8 u16 = A_hat[j0+kg*8+jj][d0+fr], jj=0..7.
//   A B-fragment/A^T-fragment load is then one contiguous 1KB wave read.
// ---------------------------------------------------------------------------
__global__ __launch_bounds__(256) void transpose_ahat(
    const ushort* __restrict__ Asw, ushort* __restrict__ Asw2)
{
    const int t = threadIdx.x, w = t >> 6, lane = t & 63;
    const int fr = lane & 15, kg = lane >> 4;
    const int b = blockIdx.x;                 // 64 blocks
    const int j0 = b * 128 + w * 32;          // wave's 32-row j-block

    #pragma unroll 1
    for (int D = 0; D < 16; ++D) {
        const int d = D * 16 + fr;
        ushort v[8];
        #pragma unroll
        for (int jj = 0; jj < 8; ++jj) {
            const int J = j0 + kg * 8 + jj;
            v[jj] = Asw[(size_t)(J >> 4) * 4096 + (d >> 5) * 512
                        + ((d >> 3) & 3) * 128 + (J & 15) * 8 + (d & 7)];
        }
        uint4 pk;
        pk.x = v[0] | ((unsigned)v[1] << 16);
        pk.y = v[2] | ((unsigned)v[3] << 16);
        pk.z = v[4] | ((unsigned)v[5] << 16);
        pk.w = v[6] | ((unsigned)v[7] << 16);
        *reinterpret_cast<uint4*>(
            Asw2 + (size_t)(D * 256 + b * 4 + w) * 512 + (size_t)lane * 8) = pk;
    }
}

// ---------------------------------------------------------------------------
// Kernel G: Gram partials  M = A_hat^T A_hat  (256x256), K split in 32 chunks.
// Block (kc, h): k-rows [kc*256,+256), M-rows [h*128,+128); 4 waves split cols.
// Both A^T-frags and B-frags come from layout-2 (identical access pattern).
// ---------------------------------------------------------------------------
__global__ __launch_bounds__(256, 2) void gram(
    const ushort* __restrict__ Asw2, float* __restrict__ Mpart)
{
    const int t = threadIdx.x, w = t >> 6, lane = t & 63;
    const int fr = lane & 15, kg = lane >> 4;
    const int kc = blockIdx.x;   // 0..31
    const int h  = blockIdx.y;   // 0..1

    f32x4 acc[8][4] = {};
    #pragma unroll 1
    for (int k32 = 0; k32 < 8; ++k32) {
        const int j5 = (kc * 256 + k32 * 32) >> 5;
        s16x8 af[8], bf[4];
        #pragma unroll
        for (int m = 0; m < 8; ++m)
            af[m] = *reinterpret_cast<const s16x8*>(
                Asw2 + ((size_t)((h * 8 + m) * 256 + j5)) * 512 + lane * 8);
        #pragma unroll
        for (int n = 0; n < 4; ++n)
            bf[n] = *reinterpret_cast<const s16x8*>(
                Asw2 + ((size_t)((w * 4 + n) * 256 + j5)) * 512 + lane * 8);
        #pragma unroll
        for (int m = 0; m < 8; ++m)
            #pragma unroll
            for (int n = 0; n < 4; ++n)
                acc[m][n] = __builtin_amdgcn_mfma_f32_16x16x32_bf16(
                    af[m], bf[n], acc[m][n], 0, 0, 0);
    }
    // C layout: col = lane&15, row = (lane>>4)*4 + reg
    float* base = Mpart + (size_t)kc * 65536
                + (size_t)(h * 128 + kg * 4) * 256 + w * 64 + fr;
    #pragma unroll
    for (int m = 0; m < 8; ++m)
        #pragma unroll
        for (int reg = 0; reg < 4; ++reg)
            #pragma unroll
            for (int n = 0; n < 4; ++n)
                base[(size_t)(m * 16 + reg) * 256 + n * 16] = acc[m][n][reg];
}

// ---------------------------------------------------------------------------
// Kernel GR: sum the 32 Gram partials per entry, square, reduce -> gpart[64]
// ---------------------------------------------------------------------------
__global__ __launch_bounds__(256) void gram_reduce(
    const float* __restrict__ Mpart, float* __restrict__ gpart)
{
    __shared__ float sh[4];
    const int t = threadIdx.x;
    const int id = blockIdx.x * 256 + t;      // 64 blocks -> 16384 threads
    float ss = 0.f;
    for (int e = id; e < 65536; e += 16384) {
        float s = 0.f;
        #pragma unroll 4
        for (int kc = 0; kc < 32; ++kc)
            s += Mpart[(size_t)kc * 65536 + e];
        ss += s * s;
    }
    #pragma unroll
    for (int off = 32; off > 0; off >>= 1) ss += __shfl_down(ss, off);
    const int w = t >> 6, lane = t & 63;
    if (lane == 0) sh[w] = ss;
    __syncthreads();
    if (t == 0) gpart[blockIdx.x] = sh[0] + sh[1] + sh[2] + sh[3];
}

// ---------------------------------------------------------------------------
// Kernel D (the 95% kernel): streams S once.
//   Per block (256 blocks = 1/CU, 512 thr = 8 waves): i-tile 128 rows,
//   k-chunk 2048 cols, 32 rounds of 64 cols:
//     [MFMA on buf(r) w/ prefetched B-frags] -> [issue B(r+1)] ->
//     [cvt S(r+1) regs -> bf16 -> swizzled LDS, fused Sum S^2] ->
//     [issue S(r+2)] -> lgkmcnt(0) -> raw s_barrier (NO vmcnt drain).
//   B-frags always issued BEFORE the S-loads that follow them, so counted
//   vmcnt waits on B never force the HBM stream to drain.
//   Epilogue: dot(acc, A_hat rows) from layout-1 (L2 gathers) -> dotp/s2p.
// ---------------------------------------------------------------------------
__global__ __launch_bounds__(512, 2) void s_dot(
    const float* __restrict__ S, const ushort* __restrict__ Asw,
    const ushort* __restrict__ Asw2,
    float* __restrict__ dotp, float* __restrict__ s2p)
{
    __shared__ ushort sbuf[2][128 * 64];   // 2 x 16 KB bf16, XOR-swizzled chunks
    __shared__ float red[16];

    const int t = threadIdx.x;             // 0..511
    const int w = t >> 6, lane = t & 63;
    const int fr = lane & 15, kg = lane >> 4;

    const int bid = blockIdx.x;            // 256
    const int ti  = (bid >> 2) * 128;      // i-tile
    const int c0  = (bid & 3) * 2048;      // k-chunk

    // staging map: row = t>>2; thread q=t&3 owns float4s {q, q+4, q+8, q+12}
    // of the 64-col round -> per-instruction fully coalesced 64B/4-lane-group
    const int srow = t >> 2, sq = t & 3;
    const float* sg = S + (size_t)(ti + srow) * BDIM + c0 + sq * 4;

    float s2_local = 0.f;
    f32x4 acc[8][2] = {};
    float4 sv[4];
    s16x8 bcur[4], bnxt[4];

    auto load_round = [&](int r) {
        #pragma unroll
        for (int i = 0; i < 4; ++i)
            sv[i] = *reinterpret_cast<const float4*>(sg + (size_t)r * 64 + i * 16);
    };
    auto bfrag = [&](int n, int j) {
        return *reinterpret_cast<const s16x8*>(
            Asw2 + ((size_t)((w * 2 + n) * 256 + (j >> 5))) * 512 + lane * 8);
    };
    auto stage_write = [&](int buf) {
        ushort* dst = &sbuf[buf][srow * 64];
        #pragma unroll
        for (int i = 0; i < 4; ++i) {
            s2_local += sv[i].x*sv[i].x + sv[i].y*sv[i].y
                      + sv[i].z*sv[i].z + sv[i].w*sv[i].w;
            uint2 pk;
            pk.x = f2bf(sv[i].x) | ((unsigned)f2bf(sv[i].y) << 16);
            pk.y = f2bf(sv[i].z) | ((unsigned)f2bf(sv[i].w) << 16);
            const int c = i * 2 + (sq >> 1);           // 16B chunk 0..7
            *reinterpret_cast<uint2*>(
                dst + ((c ^ (srow & 7)) * 8) + (sq & 1) * 4) = pk;
        }
    };

    // ---- prologue: round 0 staged, B0 then S1 issued (B before S invariant)
    load_round(0);
    stage_write(0);
    bcur[0] = bfrag(0, c0);      bcur[1] = bfrag(1, c0);
    bcur[2] = bfrag(0, c0 + 32); bcur[3] = bfrag(1, c0 + 32);
    __builtin_amdgcn_sched_barrier(0);
    load_round(1);
    __builtin_amdgcn_sched_barrier(0);
    asm volatile("s_waitcnt lgkmcnt(0)" ::: "memory");
    __builtin_amdgcn_sched_barrier(0);
    __builtin_amdgcn_s_barrier();

    for (int r = 0; r < 32; ++r) {
        const int buf = r & 1;
        // ---- MFMA on current buffer (A from LDS, B from regs: vmcnt counted)
        #pragma unroll
        for (int kk = 0; kk < 2; ++kk)
            #pragma unroll
            for (int m = 0; m < 8; ++m) {
                const int R = m * 16 + fr;
                const s16x8 a = *reinterpret_cast<const s16x8*>(
                    &sbuf[buf][R * 64 + (((kk * 4 + kg) ^ (R & 7)) * 8)]);
                acc[m][0] = __builtin_amdgcn_mfma_f32_16x16x32_bf16(
                    a, bcur[kk * 2 + 0], acc[m][0], 0, 0, 0);
                acc[m][1] = __builtin_amdgcn_mfma_f32_16x16x32_bf16(
                    a, bcur[kk * 2 + 1], acc[m][1], 0, 0, 0);
            }
        if (r < 31) {
            const int jn = c0 + (r + 1) * 64;
            bnxt[0] = bfrag(0, jn);      bnxt[1] = bfrag(1, jn);
            bnxt[2] = bfrag(0, jn + 32); bnxt[3] = bfrag(1, jn + 32);
            __builtin_amdgcn_sched_barrier(0);
            stage_write(buf ^ 1);                  // consumes S(r+1) regs
            if (r < 30)
                load_round(r + 2);                 // S(r+2) AFTER B(r+1)
            __builtin_amdgcn_sched_barrier(0);
            asm volatile("s_waitcnt lgkmcnt(0)" ::: "memory");
            __builtin_amdgcn_sched_barrier(0);
            __builtin_amdgcn_s_barrier();          // raw: no vmcnt(0) drain
            bcur[0] = bnxt[0]; bcur[1] = bnxt[1];
            bcur[2] = bnxt[2]; bcur[3] = bnxt[3];
        }
    }

    // ---- epilogue: dot(acc, A_hat) ; row = ti+m*16+kg*4+reg, col = w*32+n*16+fr
    float dot_local = 0.f;
    #pragma unroll 1
    for (int m = 0; m < 8; ++m) {
        #pragma unroll
        for (int n = 0; n < 2; ++n) {
            const int d = w * 32 + n * 16 + fr;
            const size_t abase = (size_t)((ti >> 4) + m) * 4096
                               + (d >> 5) * 512 + ((d >> 3) & 3) * 128 + (d & 7);
            #pragma unroll
            for (int reg = 0; reg < 4; ++reg) {
                const ushort u = Asw[abase + (kg * 4 + reg) * 8];
                dot_local += __uint_as_float((unsigned)u << 16) * acc[m][n][reg];
            }
        }
    }

    #pragma unroll
    for (int off = 32; off > 0; off >>= 1) {
        dot_local += __shfl_down(dot_local, off);
        s2_local  += __shfl_down(s2_local, off);
    }
    if (lane == 0) { red[w] = dot_local; red[8 + w] = s2_local; }
    __syncthreads();
    if (t == 0) {
        float da = 0.f, sb = 0.f;
        #pragma unroll
        for (int i = 0; i < 8; ++i) { da += red[i]; sb += red[8 + i]; }
        dotp[bid] = da;
        s2p[bid]  = sb;
    }
}

// ---------------------------------------------------------------------------
// finalize: out = trip/B + (gram_ss - 2*dot + s2) / B^2
// ---------------------------------------------------------------------------
__global__ __launch_bounds__(256) void finalize(
    const float* __restrict__ pt, const float* __restrict__ dotp,
    const float* __restrict__ s2p, const float* __restrict__ gpart,
    float* __restrict__ out)
{
    __shared__ float sh[4];
    const int t = threadIdx.x;
    float trip = 0.f, sim = 0.f;
    for (int i = t; i < 2048; i += 256) trip += pt[i];
    sim += -2.f * dotp[t] + s2p[t];
    if (t < 64) sim += gpart[t];
    float v = trip * (1.0f / (float)BDIM)
            + sim  * (1.0f / ((float)BDIM * (float)BDIM));
    #pragma unroll
    for (int off = 32; off > 0; off >>= 1) v += __shfl_down(v, off);
    const int w = t >> 6, lane = t & 63;
    if (lane == 0) sh[w] = v;
    __syncthreads();
    if (t == 0) out[0] = sh[0] + sh[1] + sh[2] + sh[3];
}

extern "C" void kernel_launch(void* const* d_in, const int* in_sizes, int n_in,
                              void* d_out, int out_size, void* d_ws, size_t ws_size,
                              hipStream_t stream)
{
    const float* anchor   = (const float*)d_in[0];
    const float* positive = (const float*)d_in[1];
    const float* negative = (const float*)d_in[2];
    const float* S        = (const float*)d_in[3];
    float* out = (float*)d_out;

    float*  pt    = (float*)d_ws;                          // 2048 f
    float*  dotp  = (float*)((char*)d_ws + 8192);          // 256 f
    float*  s2p   = (float*)((char*)d_ws + 12288);         // 256 f
    float*  gpart = (float*)((char*)d_ws + 16384);         // 64 f
    ushort* Asw   = (ushort*)((char*)d_ws + (1u  << 20));  // 4 MB layout-1
    ushort* Asw2  = (ushort*)((char*)d_ws + (8u  << 20));  // 4 MB layout-2
    float*  Mpart = (float*)((char*)d_ws + (16u << 20));   // 8 MB gram partials

    row_stats<<<BDIM / 4, 256, 0, stream>>>(anchor, positive, negative, Asw, pt);
    transpose_ahat<<<64, 256, 0, stream>>>(Asw, Asw2);
    gram<<<dim3(32, 2), 256, 0, stream>>>(Asw2, Mpart);
    gram_reduce<<<64, 256, 0, stream>>>(Mpart, gpart);
    s_dot<<<256, 512, 0, stream>>>(S, Asw, Asw2, dotp, s2p);
    finalize<<<1, 256, 0, stream>>>(pt, dotp, s2p, gpart, out);
}